// Round 5
// baseline (441.646 us; speedup 1.0000x reference)
//
#include <hip/hip_runtime.h>

#define N_NODES 50000
#define N_EDGES 800000
#define SCAN_BLOCKS 196          // ceil(50000/256)
#define WIN 6250                 // dst window per XCD group (50000/8)
#define PLANE 1600000            // 50000*32 elements per dim-plane

typedef __attribute__((ext_vector_type(8))) short short8;
typedef __attribute__((ext_vector_type(4))) float f32x4;
typedef unsigned short ushort_t;
typedef unsigned int uint_t;

// ---------------- helpers ----------------
__device__ inline ushort_t f2bf(float f) {
    union { float f; uint_t u; } v; v.f = f;
    uint_t u = v.u;
    u += 0x7fffu + ((u >> 16) & 1u);   // RNE
    return (ushort_t)(u >> 16);
}
__device__ inline float bflo(uint_t v) { return __uint_as_float(v << 16); }
__device__ inline float bfhi(uint_t v) { return __uint_as_float(v & 0xffff0000u); }

// ---------------- CSR build: XCD-windowed counting sort ----------------
__global__ void count_edges_mp(const int* __restrict__ ei, int* __restrict__ cnt) {
    int g = blockIdx.x & 7;
    int nb = gridDim.x >> 3;
    int bi = blockIdx.x >> 3;
    int lo = g * WIN;
    for (int e = bi * 256 + threadIdx.x; e < N_EDGES; e += nb * 256) {
        int d = ei[N_EDGES + e];
        if ((unsigned)(d - lo) < WIN) atomicAdd(&cnt[d], 1);
    }
}

__global__ void fill_csr_mp(const int* __restrict__ ei, int* __restrict__ cursor,
                            int* __restrict__ csr_src) {
    int g = blockIdx.x & 7;
    int nb = gridDim.x >> 3;
    int bi = blockIdx.x >> 3;
    int lo = g * WIN;
    for (int e = bi * 256 + threadIdx.x; e < N_EDGES; e += nb * 256) {
        int d = ei[N_EDGES + e];
        if ((unsigned)(d - lo) < WIN) {
            int p = atomicAdd(&cursor[d], 1);
            csr_src[p] = ei[e];
        }
    }
}

__global__ void block_sums(const int* __restrict__ cnt, int* __restrict__ bsum) {
    int i = blockIdx.x * 256 + threadIdx.x;
    int v = (i < N_NODES) ? cnt[i] : 0;
    for (int off = 32; off; off >>= 1) v += __shfl_down(v, off, 64);
    __shared__ int s[4];
    if ((threadIdx.x & 63) == 0) s[threadIdx.x >> 6] = v;
    __syncthreads();
    if (threadIdx.x == 0) bsum[blockIdx.x] = s[0] + s[1] + s[2] + s[3];
}

__global__ void scan_bsums(const int* __restrict__ bsum, int* __restrict__ bprefix,
                           int* __restrict__ rowstart) {
    __shared__ int s[256];
    int t = threadIdx.x;
    int v = (t < SCAN_BLOCKS) ? bsum[t] : 0;
    s[t] = v;
    __syncthreads();
    for (int off = 1; off < 256; off <<= 1) {
        int add = (t >= off) ? s[t - off] : 0;
        __syncthreads();
        s[t] += add;
        __syncthreads();
    }
    bprefix[t] = s[t] - v;
    if (t == 0) rowstart[N_NODES] = N_EDGES;
}

__global__ void apply_scan(const int* __restrict__ cnt, const int* __restrict__ bprefix,
                           int* __restrict__ rowstart, int* __restrict__ cursor,
                           float* __restrict__ invd) {
    __shared__ int s[256];
    int t = threadIdx.x;
    int i = blockIdx.x * 256 + t;
    int v = (i < N_NODES) ? cnt[i] : 0;
    s[t] = v;
    __syncthreads();
    for (int off = 1; off < 256; off <<= 1) {
        int add = (t >= off) ? s[t - off] : 0;
        __syncthreads();
        s[t] += add;
        __syncthreads();
    }
    int excl = s[t] - v + bprefix[blockIdx.x];
    if (i < N_NODES) {
        rowstart[i] = excl; cursor[i] = excl;
        invd[i] = 1.0f / fmaxf((float)v, 1.0f);
    }
}

// ---------------- fp32 -> bf16, plane-major [4][50000][32] ----------------
__global__ void cvt_bf16_pl(const float* __restrict__ in, ushort_t* __restrict__ out) {
    int i = blockIdx.x * 256 + threadIdx.x;     // over 1.6M float4's
    if (i >= 1600000) return;
    int d0 = (i & 31) * 4;
    int node = i >> 5;
    float4 v = ((const float4*)in)[i];
    ushort4 o;
    o.x = f2bf(v.x); o.y = f2bf(v.y); o.z = f2bf(v.z); o.w = f2bf(v.w);
    int p = d0 >> 5, dd = d0 & 31;
    *(ushort4*)(out + ((size_t)p * 50000 + node) * 32 + dd) = o;
}

// ---------------- fused weight pre-pack (all 3 layers, 1 launch) ----------------
__global__ void pack_all(const float* __restrict__ Wl0, const float* __restrict__ Wr0,
                         const float* __restrict__ Wl1, const float* __restrict__ Wr1,
                         const float* __restrict__ Wl2, const float* __restrict__ Wr2,
                         ushort_t* __restrict__ pk0, ushort_t* __restrict__ pk1,
                         ushort_t* __restrict__ pkz) {
    int gi = blockIdx.x * 256 + threadIdx.x;    // 81920 total
    const float* Wl; const float* Wr; ushort_t* dst; int idx; bool zr = false;
    if (gi < 32768)       { Wl = Wl0; Wr = Wr0; dst = pk0; idx = gi; }
    else if (gi < 65536)  { Wl = Wl1; Wr = Wr1; dst = pk1; idx = gi - 32768; }
    else if (gi < 81920)  { Wl = Wl2; Wr = Wr2; dst = pkz; idx = gi - 65536; zr = true; }
    else return;
    int j = idx & 7, l = (idx >> 3) & 63, t = (idx >> 9) & 7, ks = idx >> 12;
    int n = t * 16 + (l & 15);
    int k = ks * 32 + (l >> 4) * 8 + j;
    float w;
    if (zr) w = (n < 64) ? Wl[k * 64 + n] : Wr[k * 64 + (n - 64)];
    else    w = (k < 128) ? Wl[k * 128 + n] : Wr[(k - 128) * 128 + n];
    dst[idx] = f2bf(w);
}

// ---------------- wave-per-node plane-sliced mean aggregation ----------------
// role = blockIdx&7 -> XCD; slice s = role>>1 owns L2-resident dim-plane s
// (3.2 MB); half = role&1 owns 25000 dst nodes. One wave streams ~25
// consecutive nodes: sub = lane>>4 takes edge e+sub (csr index via direct
// broadcast load, +imm offsets, L1-hot), 16 lanes cover the 64B slice row.
// No shfl/masks in the main loop (tail masked once per node); scalars via
// readfirstlane so loop control is SALU; 4 gathers in flight per quad.
__global__ __launch_bounds__(256) void agg_w(
    const ushort_t* __restrict__ feat_pl,       // [4][50000][32] bf16
    const int* __restrict__ rowstart,
    const int* __restrict__ csr_src,
    ushort_t* __restrict__ sum_pl) {            // [4][50000][32] bf16 sums
    int role = blockIdx.x & 7;
    int bi   = blockIdx.x >> 3;                 // 0..255
    int s = role >> 1, h = role & 1;
    int lane = threadIdx.x & 63, wave = threadIdx.x >> 6;
    int wid = bi * 4 + wave;                    // 0..1023 per role
    int n0 = h * 25000 + wid * 25;
    int n1 = min(n0 + 25, (h + 1) * 25000);
    if (n0 >= n1) return;
    int sub = lane >> 4, sl = lane & 15;
    const uint_t* pb = (const uint_t*)feat_pl + (size_t)s * (PLANE / 2);
    uint_t* mb = (uint_t*)sum_pl + (size_t)s * (PLANE / 2);

    int e = __builtin_amdgcn_readfirstlane(rowstart[n0]);
    for (int node = n0; node < n1; ++node) {
        int s1 = __builtin_amdgcn_readfirstlane(rowstart[node + 1]);
        float a0 = 0.f, a1 = 0.f, b0 = 0.f, b1 = 0.f;
        // quad batches: 16 edges, 4 gathers in flight
        while (e + 16 <= s1) {
            const int* cp = csr_src + e + sub;
            int i0 = __builtin_nontemporal_load(cp);
            int i1 = __builtin_nontemporal_load(cp + 4);
            int i2 = __builtin_nontemporal_load(cp + 8);
            int i3 = __builtin_nontemporal_load(cp + 12);
            uint_t v0 = pb[((uint_t)i0 << 4) + sl];
            uint_t v1 = pb[((uint_t)i1 << 4) + sl];
            uint_t v2 = pb[((uint_t)i2 << 4) + sl];
            uint_t v3 = pb[((uint_t)i3 << 4) + sl];
            a0 += bflo(v0); a1 += bfhi(v0);
            b0 += bflo(v1); b1 += bfhi(v1);
            a0 += bflo(v2); a1 += bfhi(v2);
            b0 += bflo(v3); b1 += bfhi(v3);
            e += 16;
        }
        // single batches: 4 edges
        while (e + 4 <= s1) {
            int i0 = __builtin_nontemporal_load(csr_src + e + sub);
            uint_t v0 = pb[((uint_t)i0 << 4) + sl];
            a0 += bflo(v0); a1 += bfhi(v0);
            e += 4;
        }
        // tail: 0..3 edges, masked once
        if (e < s1) {
            int i0 = __builtin_nontemporal_load(csr_src + min(e + sub, N_EDGES - 1));
            uint_t v0 = pb[((uint_t)i0 << 4) + sl];
            if (e + sub >= s1) v0 = 0;
            a0 += bflo(v0); a1 += bfhi(v0);
            e = s1;
        }
        a0 += b0; a1 += b1;
        // cross-sub reduce (4 subs hold partial sums of the same node)
        a0 += __shfl_xor(a0, 16, 64); a0 += __shfl_xor(a0, 32, 64);
        a1 += __shfl_xor(a1, 16, 64); a1 += __shfl_xor(a1, 32, 64);
        if (sub == 0) {
            uint_t r;
            asm("v_cvt_pk_bf16_f32 %0, %1, %2" : "=v"(r) : "v"(a0), "v"(a1));
            __builtin_nontemporal_store(r, &mb[(size_t)node * 16 + sl]);
        }
    }
}

// ---------------- MFMA GEMM, plane in/out, B staged in LDS ----------------
// h = relu(diag(inv) * (sum @ Wl) + root @ Wr + b), plane-major tensors.
__global__ __launch_bounds__(256) void gemm_pl(
    const ushort_t* __restrict__ sum_pl, const ushort_t* __restrict__ root_pl,
    const ushort_t* __restrict__ Bpk, const float* __restrict__ bias,
    const float* __restrict__ invd,
    ushort_t* __restrict__ out_pl) {
    __shared__ ushort_t bsh[32768];             // 64 KB B-pack
    {
        const uint4* src = (const uint4*)Bpk;
        uint4* dst = (uint4*)bsh;
        for (int i = threadIdx.x; i < 4096; i += 256) dst[i] = src[i];
    }
    __syncthreads();

    int lane = threadIdx.x & 63;
    int wave = threadIdx.x >> 6;
    int row16 = lane & 15;
    int quad = lane >> 4;
    int rowBase = blockIdx.x * 64 + wave * 16;
    int arow = min(rowBase + row16, N_NODES - 1);
    const short8* bp = (const short8*)bsh + lane;

    f32x4 acc[8];
    #pragma unroll
    for (int t = 0; t < 8; ++t) { f32x4 z = {0.f, 0.f, 0.f, 0.f}; acc[t] = z; }

    // mean part: sum planes, scaled by invd after the partial accumulation
    #pragma unroll
    for (int ks = 0; ks < 4; ++ks) {
        short8 afrag = *(const short8*)(sum_pl + ((size_t)ks * 50000 + arow) * 32 + quad * 8);
        #pragma unroll
        for (int t = 0; t < 8; ++t) {
            short8 bfrag = bp[(ks * 8 + t) * 64];
            acc[t] = __builtin_amdgcn_mfma_f32_16x16x32_bf16(afrag, bfrag, acc[t], 0, 0, 0);
        }
    }
    {
        float4 iv = *(const float4*)(invd + rowBase + quad * 4);
        #pragma unroll
        for (int t = 0; t < 8; ++t) {
            acc[t][0] *= iv.x; acc[t][1] *= iv.y;
            acc[t][2] *= iv.z; acc[t][3] *= iv.w;
        }
    }
    // root part
    #pragma unroll
    for (int ks = 4; ks < 8; ++ks) {
        short8 afrag = *(const short8*)(root_pl + ((size_t)(ks - 4) * 50000 + arow) * 32 + quad * 8);
        #pragma unroll
        for (int t = 0; t < 8; ++t) {
            short8 bfrag = bp[(ks * 8 + t) * 64];
            acc[t] = __builtin_amdgcn_mfma_f32_16x16x32_bf16(afrag, bfrag, acc[t], 0, 0, 0);
        }
    }

    #pragma unroll
    for (int t = 0; t < 8; ++t) {
        int col = t * 16 + row16;
        float bv = bias[col];
        int pl = col >> 5, dd = col & 31;
        #pragma unroll
        for (int r = 0; r < 4; ++r) {
            int row = rowBase + quad * 4 + r;
            if (row < N_NODES) {
                float v = fmaxf(acc[t][r] + bv, 0.f);
                out_pl[((size_t)pl * 50000 + row) * 32 + dd] = f2bf(v);
            }
        }
    }
}

// ---------------- layer-2 pre-transform: [z | r] = h @ [Wl2 | Wr2], r += b2 ----------------
// z written as 2 L2-resident planes [2][50000][32] for the final gather.
__global__ __launch_bounds__(256) void gemm_zr_pl(
    const ushort_t* __restrict__ h_pl, const ushort_t* __restrict__ Bpk,
    const float* __restrict__ bias,
    ushort_t* __restrict__ z_pl, float* __restrict__ r_f32) {
    __shared__ ushort_t bsh[16384];             // 32 KB B-pack
    {
        const uint4* src = (const uint4*)Bpk;
        uint4* dst = (uint4*)bsh;
        for (int i = threadIdx.x; i < 2048; i += 256) dst[i] = src[i];
    }
    __syncthreads();

    int lane = threadIdx.x & 63;
    int wave = threadIdx.x >> 6;
    int row16 = lane & 15;
    int quad = lane >> 4;
    int rowBase = blockIdx.x * 64 + wave * 16;
    int arow = min(rowBase + row16, N_NODES - 1);
    const short8* bp = (const short8*)bsh + lane;

    f32x4 acc[8];
    #pragma unroll
    for (int t = 0; t < 8; ++t) { f32x4 z = {0.f, 0.f, 0.f, 0.f}; acc[t] = z; }

    #pragma unroll
    for (int ks = 0; ks < 4; ++ks) {
        short8 afrag = *(const short8*)(h_pl + ((size_t)ks * 50000 + arow) * 32 + quad * 8);
        #pragma unroll
        for (int t = 0; t < 8; ++t) {
            short8 bfrag = bp[(ks * 8 + t) * 64];
            acc[t] = __builtin_amdgcn_mfma_f32_16x16x32_bf16(afrag, bfrag, acc[t], 0, 0, 0);
        }
    }

    #pragma unroll
    for (int t = 0; t < 8; ++t) {
        int col = t * 16 + row16;
        #pragma unroll
        for (int r = 0; r < 4; ++r) {
            int row = rowBase + quad * 4 + r;
            if (row < N_NODES) {
                if (col < 64) {
                    z_pl[((size_t)(col >> 5) * 50000 + row) * 32 + (col & 31)] = f2bf(acc[t][r]);
                } else {
                    r_f32[(size_t)row * 64 + (col - 64)] = acc[t][r] + bias[col - 64];
                }
            }
        }
    }
}

// ---------------- wave-per-node final gather: f32 sums of z[src] ----------------
// Same skeleton as agg_w; role = blockIdx&7: s = role>>2 (2 z-planes),
// q = role&3 (node quarter).
__global__ __launch_bounds__(256) void fin_w(
    const ushort_t* __restrict__ z_pl,
    const int* __restrict__ rowstart,
    const int* __restrict__ csr_src,
    float* __restrict__ fsum) {                 // [2][50000][32] f32
    int role = blockIdx.x & 7;
    int bi   = blockIdx.x >> 3;                 // 0..255
    int s = role >> 2, q = role & 3;
    int lane = threadIdx.x & 63, wave = threadIdx.x >> 6;
    int wid = bi * 4 + wave;                    // 0..1023 per role
    int n0 = q * 12500 + wid * 13;
    int n1 = min(n0 + 13, (q + 1) * 12500);
    if (n0 >= n1) return;
    int sub = lane >> 4, sl = lane & 15;
    const uint_t* pb = (const uint_t*)z_pl + (size_t)s * (PLANE / 2);
    float* fb = fsum + (size_t)s * PLANE;

    int e = __builtin_amdgcn_readfirstlane(rowstart[n0]);
    for (int node = n0; node < n1; ++node) {
        int s1 = __builtin_amdgcn_readfirstlane(rowstart[node + 1]);
        float a0 = 0.f, a1 = 0.f, b0 = 0.f, b1 = 0.f;
        while (e + 16 <= s1) {
            const int* cp = csr_src + e + sub;
            int i0 = __builtin_nontemporal_load(cp);
            int i1 = __builtin_nontemporal_load(cp + 4);
            int i2 = __builtin_nontemporal_load(cp + 8);
            int i3 = __builtin_nontemporal_load(cp + 12);
            uint_t v0 = pb[((uint_t)i0 << 4) + sl];
            uint_t v1 = pb[((uint_t)i1 << 4) + sl];
            uint_t v2 = pb[((uint_t)i2 << 4) + sl];
            uint_t v3 = pb[((uint_t)i3 << 4) + sl];
            a0 += bflo(v0); a1 += bfhi(v0);
            b0 += bflo(v1); b1 += bfhi(v1);
            a0 += bflo(v2); a1 += bfhi(v2);
            b0 += bflo(v3); b1 += bfhi(v3);
            e += 16;
        }
        while (e + 4 <= s1) {
            int i0 = __builtin_nontemporal_load(csr_src + e + sub);
            uint_t v0 = pb[((uint_t)i0 << 4) + sl];
            a0 += bflo(v0); a1 += bfhi(v0);
            e += 4;
        }
        if (e < s1) {
            int i0 = __builtin_nontemporal_load(csr_src + min(e + sub, N_EDGES - 1));
            uint_t v0 = pb[((uint_t)i0 << 4) + sl];
            if (e + sub >= s1) v0 = 0;
            a0 += bflo(v0); a1 += bfhi(v0);
            e = s1;
        }
        a0 += b0; a1 += b1;
        a0 += __shfl_xor(a0, 16, 64); a0 += __shfl_xor(a0, 32, 64);
        a1 += __shfl_xor(a1, 16, 64); a1 += __shfl_xor(a1, 32, 64);
        if (sub == 0) {
            __builtin_nontemporal_store(a0, &fb[(size_t)node * 32 + (sl << 1)]);
            __builtin_nontemporal_store(a1, &fb[(size_t)node * 32 + (sl << 1) + 1]);
        }
    }
}

// ---------------- final streaming softmax: h = fsum*inv + r; log_softmax ----------------
__global__ __launch_bounds__(256) void softmax_fin(
    const float* __restrict__ fsum, const float* __restrict__ r_f32,
    const float* __restrict__ invd, float* __restrict__ out) {
    int node = blockIdx.x * 4 + (threadIdx.x >> 6);
    int d = threadIdx.x & 63;
    if (node >= N_NODES) return;
    float inv = invd[node];
    float sum = fsum[(size_t)(d >> 5) * PLANE + (size_t)node * 32 + (d & 31)];
    float h = sum * inv + r_f32[(size_t)node * 64 + d];

    float mx = h;
    for (int off = 32; off; off >>= 1) mx = fmaxf(mx, __shfl_xor(mx, off, 64));
    float e = expf(h - mx);
    float ssum = e;
    for (int off = 32; off; off >>= 1) ssum += __shfl_xor(ssum, off, 64);
    float lse = mx + logf(ssum);

    out[(size_t)node * 64 + d] = h - lse;
    out[(size_t)N_NODES * 64 + (size_t)node * 64 + d] = h;
}

extern "C" void kernel_launch(void* const* d_in, const int* in_sizes, int n_in,
                              void* d_out, int out_size, void* d_ws, size_t ws_size,
                              hipStream_t stream) {
    const float* x  = (const float*)d_in[0];
    const int* ei   = (const int*)d_in[1];
    const float* Wl0 = (const float*)d_in[2];
    const float* Wr0 = (const float*)d_in[3];
    const float* b0  = (const float*)d_in[4];
    const float* Wl1 = (const float*)d_in[5];
    const float* Wr1 = (const float*)d_in[6];
    const float* b1  = (const float*)d_in[7];
    const float* Wl2 = (const float*)d_in[8];
    const float* Wr2 = (const float*)d_in[9];
    const float* b2  = (const float*)d_in[10];
    float* out = (float*)d_out;

    char* ws = (char*)d_ws;
    int* cnt      = (int*)(ws + 0x000000);
    int* rowstart = (int*)(ws + 0x040000);
    int* cursor   = (int*)(ws + 0x080000);
    int* bsum     = (int*)(ws + 0x0C0000);
    int* bprefix  = (int*)(ws + 0x0C1000);
    int* csr_src  = (int*)(ws + 0x100000);            // 3.2 MB
    ushort_t* pk0 = (ushort_t*)(ws + 0x420000);       // 64 KB
    ushort_t* pk1 = (ushort_t*)(ws + 0x440000);       // 64 KB
    ushort_t* pkz = (ushort_t*)(ws + 0x460000);       // 32 KB
    float* invd   = (float*)(ws + 0x480000);          // 200 KB
    ushort_t* x_pl    = (ushort_t*)(ws + 0x0500000);  // 12.8 MB  [4][50000][32]
    ushort_t* sum_pl  = (ushort_t*)(ws + 0x1200000);  // 12.8 MB  bf16 sums
    ushort_t* h_pl    = (ushort_t*)(ws + 0x1F00000);  // 12.8 MB
    ushort_t* h2_pl   = (ushort_t*)(ws + 0x2C00000);  // 12.8 MB
    ushort_t* z_pl    = (ushort_t*)(ws + 0x3900000);  // 6.4 MB  [2][50000][32]
    float*    r_f32   = (float*)  (ws + 0x4000000);   // 12.8 MB
    float*    fsum    = (float*)  (ws + 0x4D00000);   // 12.8 MB [2][50000][32] f32

    // ---- weight pre-pack (overlaps CSR build) ----
    pack_all<<<320, 256, 0, stream>>>(Wl0, Wr0, Wl1, Wr1, Wl2, Wr2, pk0, pk1, pkz);

    // ---- CSR build (XCD-windowed counting sort) ----
    hipMemsetAsync(cnt, 0, N_NODES * sizeof(int), stream);
    count_edges_mp<<<1024, 256, 0, stream>>>(ei, cnt);
    block_sums<<<SCAN_BLOCKS, 256, 0, stream>>>(cnt, bsum);
    scan_bsums<<<1, 256, 0, stream>>>(bsum, bprefix, rowstart);
    apply_scan<<<SCAN_BLOCKS, 256, 0, stream>>>(cnt, bprefix, rowstart, cursor, invd);
    fill_csr_mp<<<1024, 256, 0, stream>>>(ei, cursor, csr_src);

    // ---- x -> bf16 planes ----
    cvt_bf16_pl<<<6250, 256, 0, stream>>>(x, x_pl);

    // ---- layer 0 ----
    agg_w<<<2048, 256, 0, stream>>>(x_pl, rowstart, csr_src, sum_pl);
    gemm_pl<<<782, 256, 0, stream>>>(sum_pl, x_pl, pk0, b0, invd, h_pl);

    // ---- layer 1 ----
    agg_w<<<2048, 256, 0, stream>>>(h_pl, rowstart, csr_src, sum_pl);
    gemm_pl<<<782, 256, 0, stream>>>(sum_pl, h_pl, pk1, b1, invd, h2_pl);

    // ---- layer 2: transform-first, wave-per-node final gather, streaming softmax ----
    gemm_zr_pl<<<782, 256, 0, stream>>>(h2_pl, pkz, b2, z_pl, r_f32);
    fin_w<<<2048, 256, 0, stream>>>(z_pl, rowstart, csr_src, fsum);
    softmax_fin<<<12500, 256, 0, stream>>>(fsum, r_f32, invd, out);
}

// Round 6
// 276.083 us; speedup vs baseline: 1.5997x; 1.5997x over previous
//
#include <hip/hip_runtime.h>

#define N_NODES 50000
#define N_EDGES 800000
#define SCAN_BLOCKS 196          // ceil(50000/256)
#define WIN 6250                 // dst window per XCD group (50000/8)

typedef __attribute__((ext_vector_type(8))) short short8;
typedef __attribute__((ext_vector_type(4))) float f32x4;
typedef unsigned short ushort_t;
typedef unsigned int uint_t;

// ---------------- helpers ----------------
__device__ inline ushort_t f2bf(float f) {
    union { float f; uint_t u; } v; v.f = f;
    uint_t u = v.u;
    u += 0x7fffu + ((u >> 16) & 1u);   // RNE
    return (ushort_t)(u >> 16);
}
__device__ inline float bflo(uint_t v) { return __uint_as_float(v << 16); }
__device__ inline float bfhi(uint_t v) { return __uint_as_float(v & 0xffff0000u); }
__device__ inline float bf2f(ushort_t v) { return __uint_as_float((uint_t)v << 16); }

#define ACC8(V) { a[0] += bflo((V).x); a[1] += bfhi((V).x); \
                  a[2] += bflo((V).y); a[3] += bfhi((V).y); \
                  a[4] += bflo((V).z); a[5] += bfhi((V).z); \
                  a[6] += bflo((V).w); a[7] += bfhi((V).w); }

// ---------------- fused prep: edge count + fp32->bf16 cvt + weight packs ----------------
// blocks 0..1023: XCD-windowed dst counting (blockIdx&7 -> XCD role preserved)
// blocks 1024..7273: x -> bf16 (row-major [50000][128])
// blocks 7274..7593: pack all 3 layer B-fragments
__global__ void prep(const int* __restrict__ ei, int* __restrict__ cnt,
                     const float* __restrict__ x, ushort_t* __restrict__ x_bf,
                     const float* __restrict__ Wl0, const float* __restrict__ Wr0,
                     const float* __restrict__ Wl1, const float* __restrict__ Wr1,
                     const float* __restrict__ Wl2, const float* __restrict__ Wr2,
                     ushort_t* __restrict__ pk0, ushort_t* __restrict__ pk1,
                     ushort_t* __restrict__ pkz) {
    int b = blockIdx.x;
    if (b < 1024) {
        int g = b & 7;
        int bi = b >> 3;
        int lo = g * WIN;
        for (int e = bi * 256 + threadIdx.x; e < N_EDGES; e += 128 * 256) {
            int d = ei[N_EDGES + e];
            if ((unsigned)(d - lo) < WIN) atomicAdd(&cnt[d], 1);
        }
    } else if (b < 7274) {
        int i = (b - 1024) * 256 + threadIdx.x;
        if (i < 1600000) {
            float4 v = ((const float4*)x)[i];
            ushort4 o;
            o.x = f2bf(v.x); o.y = f2bf(v.y); o.z = f2bf(v.z); o.w = f2bf(v.w);
            ((ushort4*)x_bf)[i] = o;
        }
    } else {
        int gi = (b - 7274) * 256 + threadIdx.x;    // 81920 total
        const float* Wl; const float* Wr; ushort_t* dst; int idx; bool zr = false;
        if (gi < 32768)       { Wl = Wl0; Wr = Wr0; dst = pk0; idx = gi; }
        else if (gi < 65536)  { Wl = Wl1; Wr = Wr1; dst = pk1; idx = gi - 32768; }
        else if (gi < 81920)  { Wl = Wl2; Wr = Wr2; dst = pkz; idx = gi - 65536; zr = true; }
        else return;
        int j = idx & 7, l = (idx >> 3) & 63, t = (idx >> 9) & 7, ks = idx >> 12;
        int n = t * 16 + (l & 15);
        int k = ks * 32 + (l >> 4) * 8 + j;
        float w;
        if (zr) w = (n < 64) ? Wl[k * 64 + n] : Wr[k * 64 + (n - 64)];
        else    w = (k < 128) ? Wl[k * 128 + n] : Wr[(k - 128) * 128 + n];
        dst[idx] = f2bf(w);
    }
}

// ---------------- CSR build (scan chain + fill) ----------------
__global__ void fill_csr_mp(const int* __restrict__ ei, int* __restrict__ cursor,
                            int* __restrict__ csr_src) {
    int g = blockIdx.x & 7;
    int nb = gridDim.x >> 3;
    int bi = blockIdx.x >> 3;
    int lo = g * WIN;
    for (int e = bi * 256 + threadIdx.x; e < N_EDGES; e += nb * 256) {
        int d = ei[N_EDGES + e];
        if ((unsigned)(d - lo) < WIN) {
            int p = atomicAdd(&cursor[d], 1);
            csr_src[p] = ei[e];
        }
    }
}

__global__ void block_sums(const int* __restrict__ cnt, int* __restrict__ bsum) {
    int i = blockIdx.x * 256 + threadIdx.x;
    int v = (i < N_NODES) ? cnt[i] : 0;
    for (int off = 32; off; off >>= 1) v += __shfl_down(v, off, 64);
    __shared__ int s[4];
    if ((threadIdx.x & 63) == 0) s[threadIdx.x >> 6] = v;
    __syncthreads();
    if (threadIdx.x == 0) bsum[blockIdx.x] = s[0] + s[1] + s[2] + s[3];
}

__global__ void scan_bsums(const int* __restrict__ bsum, int* __restrict__ bprefix,
                           int* __restrict__ rowstart) {
    __shared__ int s[256];
    int t = threadIdx.x;
    int v = (t < SCAN_BLOCKS) ? bsum[t] : 0;
    s[t] = v;
    __syncthreads();
    for (int off = 1; off < 256; off <<= 1) {
        int add = (t >= off) ? s[t - off] : 0;
        __syncthreads();
        s[t] += add;
        __syncthreads();
    }
    bprefix[t] = s[t] - v;
    if (t == 0) rowstart[N_NODES] = N_EDGES;
}

__global__ void apply_scan(const int* __restrict__ cnt, const int* __restrict__ bprefix,
                           int* __restrict__ rowstart, int* __restrict__ cursor) {
    __shared__ int s[256];
    int t = threadIdx.x;
    int i = blockIdx.x * 256 + t;
    int v = (i < N_NODES) ? cnt[i] : 0;
    s[t] = v;
    __syncthreads();
    for (int off = 1; off < 256; off <<= 1) {
        int add = (t >= off) ? s[t - off] : 0;
        __syncthreads();
        s[t] += add;
        __syncthreads();
    }
    int excl = s[t] - v + bprefix[blockIdx.x];
    if (i < N_NODES) { rowstart[i] = excl; cursor[i] = excl; }
}

// ---------------- fused layer: mean-aggregate -> LDS -> MFMA GEMM (-> optional 2nd GEMM) ----------------
// Proven R1 structure (43.7us): block = 4 waves, 64 nodes; aggregation gathers
// four 256B rows per wave instruction (16 lanes x dwordx4); mean tile in LDS
// (stride 68 uints); GEMM-1 computes h = relu([mean|root]@[Wl;Wr]+b).
// ZR=true (layer 1): h2 tile stays in LDS (never touches memory) and a second
// MFMA pass computes [z|r] = h2 @ [Wl2|Wr2] (+b2 on r) directly.
template <bool ZR>
__global__ __launch_bounds__(256) void sage_fused_k(
    const ushort_t* __restrict__ feat_bf,
    const int* __restrict__ rowstart,
    const int* __restrict__ csr_src,
    const ushort_t* __restrict__ Bpk, const float* __restrict__ bias,
    const ushort_t* __restrict__ Bz, const float* __restrict__ bias2,
    ushort_t* __restrict__ out_bf,
    ushort_t* __restrict__ z_bf, float* __restrict__ r_f32) {
    __shared__ uint_t mlds[64][68];
    int lane = threadIdx.x & 63;
    int wave = threadIdx.x >> 6;
    int rowBase = blockIdx.x * 64 + wave * 16;
    int sub = lane >> 4;                  // node slot within wave pass
    int sl  = lane & 15;                  // lane within node row
    int gb  = sub << 4;
    const uint_t* base = (const uint_t*)feat_bf;

    for (int p = 0; p < 4; ++p) {
        int node = rowBase + p * 4 + sub;
        int s0 = 0, s1 = 0;
        if (node < N_NODES) { s0 = rowstart[node]; s1 = rowstart[node + 1]; }
        float a[8];
        #pragma unroll
        for (int k = 0; k < 8; ++k) a[k] = 0.f;

        int pos = s0;
        while (__any(pos < s1)) {
            int m = min(16, s1 - pos);               // group-uniform, may be <=0
            int idxr = (sl < m) ? csr_src[pos + sl] : 0;
            int mm = max(m, 0);
            mm = max(mm, __shfl_xor(mm, 16, 64));
            mm = max(mm, __shfl_xor(mm, 32, 64));
            for (int j = 0; j < mm; j += 8) {
                int  sidx[8];
                bool vld[8];
                #pragma unroll
                for (int k = 0; k < 8; ++k) {
                    int q = __shfl(idxr, (gb + j + k) & 63, 64);
                    vld[k]  = (j + k < m);
                    sidx[k] = vld[k] ? q : 0;        // safe clamped addr, result discarded
                }
                uint4 V[8];
                #pragma unroll
                for (int k = 0; k < 8; ++k)
                    V[k] = *(const uint4*)(base + (size_t)sidx[k] * 64 + (sl << 2));
                #pragma unroll
                for (int k = 0; k < 8; ++k)
                    if (vld[k]) { ACC8(V[k]); }
            }
            pos += 16;
        }
        float inv = 1.0f / fmaxf((float)(s1 - s0), 1.0f);
        uint4 o;
        o.x = (uint_t)f2bf(a[0] * inv) | ((uint_t)f2bf(a[1] * inv) << 16);
        o.y = (uint_t)f2bf(a[2] * inv) | ((uint_t)f2bf(a[3] * inv) << 16);
        o.z = (uint_t)f2bf(a[4] * inv) | ((uint_t)f2bf(a[5] * inv) << 16);
        o.w = (uint_t)f2bf(a[6] * inv) | ((uint_t)f2bf(a[7] * inv) << 16);
        *((uint4*)&mlds[wave * 16 + p * 4 + sub][sl << 2]) = o;
    }
    __syncthreads();

    // ---- GEMM-1: A = [mean(LDS) | root(global)], B pre-packed ----
    int row16 = lane & 15;
    int quad  = lane >> 4;
    int arow  = min(rowBase + row16, N_NODES - 1);
    const ushort_t* rrow = feat_bf + (size_t)arow * 128;
    const short8* bp = (const short8*)Bpk + lane;

    f32x4 acc[8];
    #pragma unroll
    for (int t = 0; t < 8; ++t) { f32x4 z = {0.f, 0.f, 0.f, 0.f}; acc[t] = z; }

    #pragma unroll
    for (int ks = 0; ks < 8; ++ks) {
        short8 afrag;
        if (ks < 4)
            afrag = *(const short8*)&mlds[wave * 16 + row16][ks * 16 + quad * 4];
        else
            afrag = *(const short8*)(rrow + (ks - 4) * 32 + quad * 8);
        #pragma unroll
        for (int t = 0; t < 8; ++t) {
            short8 bfrag = bp[(ks * 8 + t) * 64];
            acc[t] = __builtin_amdgcn_mfma_f32_16x16x32_bf16(afrag, bfrag, acc[t], 0, 0, 0);
        }
    }

    if (!ZR) {
        #pragma unroll
        for (int t = 0; t < 8; ++t) {
            int col = t * 16 + row16;
            float bv = bias[col];
            #pragma unroll
            for (int r = 0; r < 4; ++r) {
                int row = rowBase + quad * 4 + r;
                if (row < N_NODES) {
                    float v = fmaxf(acc[t][r] + bv, 0.f);
                    out_bf[(size_t)row * 128 + col] = f2bf(v);
                }
            }
        }
    } else {
        // h2 tile -> LDS (reuse mean tile; all rows wave-local, mean already consumed)
        #pragma unroll
        for (int t = 0; t < 8; ++t) {
            int col = t * 16 + row16;
            float bv = bias[col];
            #pragma unroll
            for (int r = 0; r < 4; ++r) {
                float v = fmaxf(acc[t][r] + bv, 0.f);
                ((ushort_t*)&mlds[wave * 16 + quad * 4 + r][0])[col] = f2bf(v);
            }
        }
        __syncthreads();

        // ---- GEMM-2: [z | r] = h2(LDS) @ [Wl2 | Wr2] ----
        const short8* bz = (const short8*)Bz + lane;
        f32x4 acc2[8];
        #pragma unroll
        for (int t = 0; t < 8; ++t) { f32x4 z = {0.f, 0.f, 0.f, 0.f}; acc2[t] = z; }

        #pragma unroll
        for (int ks = 0; ks < 4; ++ks) {
            short8 afrag = *(const short8*)((const ushort_t*)&mlds[wave * 16 + row16][0]
                                            + ks * 32 + quad * 8);
            #pragma unroll
            for (int t = 0; t < 8; ++t) {
                short8 bfrag = bz[(ks * 8 + t) * 64];
                acc2[t] = __builtin_amdgcn_mfma_f32_16x16x32_bf16(afrag, bfrag, acc2[t], 0, 0, 0);
            }
        }

        #pragma unroll
        for (int t = 0; t < 8; ++t) {
            int col = t * 16 + row16;
            #pragma unroll
            for (int r = 0; r < 4; ++r) {
                int row = rowBase + quad * 4 + r;
                if (row < N_NODES) {
                    if (col < 64) {
                        z_bf[(size_t)row * 64 + col] = f2bf(acc2[t][r]);
                    } else {
                        r_f32[(size_t)row * 64 + (col - 64)] = acc2[t][r] + bias2[col - 64];
                    }
                }
            }
        }
    }
}

// ---------------- final: mean(z[src]) + r, log_softmax (8 rows/instr gather) ----------------
__global__ __launch_bounds__(256) void final_agg_softmax2(
    const ushort_t* __restrict__ z_bf, const float* __restrict__ r_f32,
    const int* __restrict__ rowstart, const int* __restrict__ csr_src,
    float* __restrict__ out) {
    int lane = threadIdx.x & 63;
    int wave = threadIdx.x >> 6;
    int sub = lane >> 3;                  // node slot 0..7
    int sl  = lane & 7;                   // lane within node row
    int gb  = sub << 3;
    int node = blockIdx.x * 32 + wave * 8 + sub;
    int s0 = 0, s1 = 0;
    if (node < N_NODES) { s0 = rowstart[node]; s1 = rowstart[node + 1]; }

    float a[8];
    #pragma unroll
    for (int k = 0; k < 8; ++k) a[k] = 0.f;
    const uint_t* zb = (const uint_t*)z_bf;

    int pos = s0;
    while (__any(pos < s1)) {
        int m = min(8, s1 - pos);
        int idxr = (sl < m) ? csr_src[pos + sl] : 0;
        int  sidx[8];
        bool vld[8];
        #pragma unroll
        for (int k = 0; k < 8; ++k) {
            int q = __shfl(idxr, (gb + k) & 63, 64);
            vld[k]  = (k < m);
            sidx[k] = vld[k] ? q : 0;
        }
        uint4 V[8];
        #pragma unroll
        for (int k = 0; k < 8; ++k)
            V[k] = *(const uint4*)(zb + (size_t)sidx[k] * 32 + (sl << 2));
        #pragma unroll
        for (int k = 0; k < 8; ++k)
            if (vld[k]) { ACC8(V[k]); }
        pos += 8;
    }
    if (node >= N_NODES) return;

    float inv = 1.0f / fmaxf((float)(s1 - s0), 1.0f);
    const float4* rr = (const float4*)(r_f32 + (size_t)node * 64 + sl * 8);
    float4 rA = rr[0], rB = rr[1];
    float h[8];
    h[0] = a[0] * inv + rA.x; h[1] = a[1] * inv + rA.y;
    h[2] = a[2] * inv + rA.z; h[3] = a[3] * inv + rA.w;
    h[4] = a[4] * inv + rB.x; h[5] = a[5] * inv + rB.y;
    h[6] = a[6] * inv + rB.z; h[7] = a[7] * inv + rB.w;

    float mx = fmaxf(fmaxf(fmaxf(h[0], h[1]), fmaxf(h[2], h[3])),
                     fmaxf(fmaxf(h[4], h[5]), fmaxf(h[6], h[7])));
    mx = fmaxf(mx, __shfl_xor(mx, 1, 64));
    mx = fmaxf(mx, __shfl_xor(mx, 2, 64));
    mx = fmaxf(mx, __shfl_xor(mx, 4, 64));
    float s = 0.f;
    #pragma unroll
    for (int k = 0; k < 8; ++k) s += expf(h[k] - mx);
    s += __shfl_xor(s, 1, 64);
    s += __shfl_xor(s, 2, 64);
    s += __shfl_xor(s, 4, 64);
    float lse = mx + logf(s);

    size_t o1 = (size_t)node * 64 + sl * 8;
    size_t o2 = (size_t)N_NODES * 64 + o1;
    *(float4*)(out + o1)     = make_float4(h[0] - lse, h[1] - lse, h[2] - lse, h[3] - lse);
    *(float4*)(out + o1 + 4) = make_float4(h[4] - lse, h[5] - lse, h[6] - lse, h[7] - lse);
    *(float4*)(out + o2)     = make_float4(h[0], h[1], h[2], h[3]);
    *(float4*)(out + o2 + 4) = make_float4(h[4], h[5], h[6], h[7]);
}

extern "C" void kernel_launch(void* const* d_in, const int* in_sizes, int n_in,
                              void* d_out, int out_size, void* d_ws, size_t ws_size,
                              hipStream_t stream) {
    const float* x  = (const float*)d_in[0];
    const int* ei   = (const int*)d_in[1];
    const float* Wl0 = (const float*)d_in[2];
    const float* Wr0 = (const float*)d_in[3];
    const float* b0  = (const float*)d_in[4];
    const float* Wl1 = (const float*)d_in[5];
    const float* Wr1 = (const float*)d_in[6];
    const float* b1  = (const float*)d_in[7];
    const float* Wl2 = (const float*)d_in[8];
    const float* Wr2 = (const float*)d_in[9];
    const float* b2  = (const float*)d_in[10];
    float* out = (float*)d_out;

    char* ws = (char*)d_ws;
    int* cnt      = (int*)(ws + 0x000000);
    int* rowstart = (int*)(ws + 0x040000);
    int* cursor   = (int*)(ws + 0x080000);
    int* bsum     = (int*)(ws + 0x0C0000);
    int* bprefix  = (int*)(ws + 0x0C1000);
    int* csr_src  = (int*)(ws + 0x100000);            // 3.2 MB
    ushort_t* pk0 = (ushort_t*)(ws + 0x420000);       // 64 KB
    ushort_t* pk1 = (ushort_t*)(ws + 0x440000);       // 64 KB
    ushort_t* pkz = (ushort_t*)(ws + 0x460000);       // 32 KB
    ushort_t* x_bf = (ushort_t*)(ws + 0x0500000);     // 12.8 MB [50000][128]
    ushort_t* h_bf = (ushort_t*)(ws + 0x1200000);     // 12.8 MB [50000][128]
    ushort_t* z_bf = (ushort_t*)(ws + 0x1F00000);     // 6.4 MB  [50000][64]
    float*    r_f32 = (float*)  (ws + 0x2600000);     // 12.8 MB [50000][64]

    // ---- prep: edge counting + x->bf16 + all weight packs (1 launch) ----
    hipMemsetAsync(cnt, 0, N_NODES * sizeof(int), stream);
    prep<<<7594, 256, 0, stream>>>(ei, cnt, x, x_bf,
                                   Wl0, Wr0, Wl1, Wr1, Wl2, Wr2, pk0, pk1, pkz);

    // ---- CSR scan + fill ----
    block_sums<<<SCAN_BLOCKS, 256, 0, stream>>>(cnt, bsum);
    scan_bsums<<<1, 256, 0, stream>>>(bsum, bprefix, rowstart);
    apply_scan<<<SCAN_BLOCKS, 256, 0, stream>>>(cnt, bprefix, rowstart, cursor);
    fill_csr_mp<<<1024, 256, 0, stream>>>(ei, cursor, csr_src);

    // ---- layer 0 (fused aggregate + GEMM): x_bf -> h_bf ----
    sage_fused_k<false><<<782, 256, 0, stream>>>(x_bf, rowstart, csr_src, pk0, b0,
                                                 nullptr, nullptr, h_bf, nullptr, nullptr);

    // ---- layer 1 + layer-2 transform fused: h_bf -> (z_bf, r_f32); h2 stays in LDS ----
    sage_fused_k<true><<<782, 256, 0, stream>>>(h_bf, rowstart, csr_src, pk1, b1,
                                                pkz, b2, nullptr, z_bf, r_f32);

    // ---- final: gather z + residual + log_softmax ----
    final_agg_softmax2<<<1563, 256, 0, stream>>>(z_bf, r_f32, rowstart, csr_src, out);
}